// Round 11
// baseline (607.478 us; speedup 1.0000x reference)
//
#include <hip/hip_runtime.h>
#include <stdint.h>

#define N_NODES  100000
#define N_EDGES  250000
#define N_GRAPHS 2000
#define F_IN     75
#define DIM      32
#define H1       128

#define MSG_BLOCKS 977           // ceil(250000/256), 256 edges per msg block
#define CH        8              // kt per LDS stage (16 KB)
#define NSTAGES   17
#define KT_PAD    (CH * NSTAGES) // 136, padded with zeros
#define W2F_HALFS (KT_PAD * 1024)

#define CNT_BLOCKS  ((N_EDGES + 255) / 256)     // 977
#define OFFS_BLOCKS ((N_NODES + 255) / 256)     // 391
#define GRUW_BLOCKS 32                          // 2x4096 halves / 256
#define W2F_BLOCKS  ((W2F_HALFS + 255) / 256)   // 544

typedef _Float16 v8h __attribute__((ext_vector_type(8)));
typedef float    v4f __attribute__((ext_vector_type(4)));

__device__ __forceinline__ void gld_lds16(const void* g, void* l) {
    __builtin_amdgcn_global_load_lds(
        (const __attribute__((address_space(1))) unsigned int*)g,
        (__attribute__((address_space(3))) unsigned int*)l, 16, 0, 0);
}

// -------- lin0: h16 = relu(nf @ W.T + b); also zeroes cnt + sbuf (replaces memsets) --------
__global__ __launch_bounds__(256) void lin0_kernel(
    const float* __restrict__ nf, const float* __restrict__ w,
    const float* __restrict__ b, _Float16* __restrict__ h16,
    float* __restrict__ cnt, float* __restrict__ sbuf) {
    __shared__ float wl[DIM * F_IN];
    __shared__ float bl[DIM];
    int t = threadIdx.x;
    for (int i = t; i < DIM * F_IN; i += 256) wl[i] = w[i];
    if (t < DIM) bl[t] = b[t];
    __syncthreads();
    int nl = t >> 5, o = t & 31;
    #pragma unroll
    for (int p = 0; p < 4; ++p) {
        int n = blockIdx.x * 32 + p * 8 + nl;
        if (n >= N_NODES) continue;
        const float* row = nf + (size_t)n * F_IN;
        float acc = bl[o];
        #pragma unroll
        for (int i = 0; i < F_IN; ++i) acc += row[i] * wl[o * F_IN + i];
        h16[(size_t)n * DIM + o] = (_Float16)fmaxf(acc, 0.f);
    }
    // zero cnt (32/block) and sbuf (1024/block)
    if (t < 32) {
        int n = blockIdx.x * 32 + t;
        if (n < N_NODES) cnt[n] = 0.f;
    }
    #pragma unroll
    for (int p = 0; p < 4; ++p) {
        size_t idx = (size_t)blockIdx.x * 1024 + p * 256 + t;
        if (idx < (size_t)N_NODES * DIM) sbuf[idx] = 0.f;
    }
}

// -------- aux: cnt atomics + graph offsets + GRU weight prepack + W2t fp16 table --------
__global__ __launch_bounds__(256) void aux_kernel(
    const int* __restrict__ dst, float* __restrict__ cnt,
    const int* __restrict__ gidx, int* __restrict__ gstart,
    const float* __restrict__ wih, const float* __restrict__ whh,
    _Float16* __restrict__ gw,
    const float* __restrict__ w2, const float* __restrict__ b2,
    _Float16* __restrict__ w2f) {
    int t = threadIdx.x;
    unsigned bx = blockIdx.x;
    if (bx < CNT_BLOCKS) {
        int e = bx * 256 + t;
        if (e < N_EDGES) atomicAdd(&cnt[dst[e]], 1.0f);
    } else if (bx < CNT_BLOCKS + OFFS_BLOCKS) {
        int n = (bx - CNT_BLOCKS) * 256 + t;
        if (n >= N_NODES) return;
        int b = gidx[n];
        if (n == 0) {
            for (int bb = 0; bb <= b; ++bb) gstart[bb] = 0;
        } else {
            int a = gidx[n - 1];
            for (int bb = a + 1; bb <= b; ++bb) gstart[bb] = n;
        }
        if (n == N_NODES - 1) {
            for (int bb = b + 1; bb <= N_GRAPHS; ++bb) gstart[bb] = N_NODES;
        }
    } else if (bx < CNT_BLOCKS + OFFS_BLOCKS + GRUW_BLOCKS) {
        int id = (bx - CNT_BLOCKS - OFFS_BLOCKS) * 256 + t;
        if (id >= 8192) return;
        int im = id & 4095;
        int r = im / 40, c = im - r * 40;
        float val = 0.f;
        if (r < 96 && c < 32) val = (id < 4096) ? wih[r * 32 + c] : whh[r * 32 + c];
        gw[id] = (_Float16)val;
    } else {
        int id = (bx - CNT_BLOCKS - OFFS_BLOCKS - GRUW_BLOCKS) * 256 + t;
        if (id >= W2F_HALFS) return;
        int j    = id & 7;
        int lane = (id >> 3) & 63;
        int ng   = (id >> 9) & 1;
        int kt   = id >> 10;
        int lr = lane & 15, q = lane >> 4;
        int c = kt * 32 + q * 8 + j;
        int o = ng * 16 + lr;
        float val = 0.f;
        if (c < 4096)      val = w2[((c >> 7) * 32 + o) * H1 + (c & 127)];
        else if (c < 4128) val = b2[(c - 4096) * 32 + o];
        w2f[id] = (_Float16)val;
    }
}

// -------- edge hidden hw, fp16 FRAG-MAJOR, 64 edges/block, coalesced 16B stores --------
// thread t -> (le_l = t>>4 in 0..15, kc8 = t&15); 4 subtiles of 16 edges
__global__ __launch_bounds__(256) void hw_kernel(
    const float* __restrict__ ef, const float* __restrict__ w1,
    const float* __restrict__ b1, _Float16* __restrict__ hwf,
    int e_off) {
    __shared__ float wl[H1 * 11];
    __shared__ float bl[H1];
    __shared__ float efl[64 * 11];
    int t = threadIdx.x;
    for (int i = t; i < H1 * 11; i += 256) wl[i] = w1[i];
    if (t < H1) bl[t] = b1[t];
    for (int i = t; i < 64 * 11; i += 256) {
        int le = i / 11, j = i - le * 11;
        int e = e_off + blockIdx.x * 64 + le;
        efl[i] = e < N_EDGES ? ef[(size_t)e * 11 + j] : 0.f;
    }
    __syncthreads();
    int le_l = t >> 4, kc8 = t & 15;
    #pragma unroll
    for (int p = 0; p < 4; ++p) {
        const float* row = &efl[(p * 16 + le_l) * 11];
        v8h outv;
        #pragma unroll
        for (int j = 0; j < 8; ++j) {
            int k = kc8 * 8 + j;
            float acc = bl[k];
            #pragma unroll
            for (int i = 0; i < 11; ++i) acc += row[i] * wl[k * 11 + i];
            outv[j] = (_Float16)fmaxf(acc, 0.f);
        }
        *(v8h*)(hwf + (size_t)(blockIdx.x * 4 + p) * 2048 + kc8 * 128 + le_l * 8) = outv;
    }
}

// -------- fused message GEMM: msg = (x[src] (x) hw) @ W2t, LDS-staged B --------
__global__ __launch_bounds__(256) void msg_kernel(
    const _Float16* __restrict__ hwf, const _Float16* __restrict__ w2f,
    const _Float16* __restrict__ x16, const int* __restrict__ src,
    const int* __restrict__ dst, float* __restrict__ sbuf, int e_off) {
    __shared__ _Float16 xs[32 * 256];        // 16 KB: xs[i][e_loc]
    __shared__ _Float16 bst[2][CH * 1024];   // 2 x 16 KB B stages

    int t = threadIdx.x;
    int w = t >> 6, lane = t & 63, lr = lane & 15, q = lane >> 4;
    int wbase = w * 64;

    {
        const char* gp = (const char*)w2f;
        char* lp = (char*)&bst[0][0];
        #pragma unroll
        for (int it = 0; it < 4; ++it)
            gld_lds16(gp + it * 4096 + t * 16, lp + it * 4096 + t * 16);
    }

    v8h hwr[4][4];
    {
        const v8h* hv = (const v8h*)hwf;
        int T0 = blockIdx.x * 16 + w * 4;
        #pragma unroll
        for (int mt = 0; mt < 4; ++mt)
            #pragma unroll
            for (int kc = 0; kc < 4; ++kc)
                hwr[mt][kc] = hv[(size_t)(T0 + mt) * 256 + (kc * 4 + q) * 16 + lr];
    }

    {
        int e = e_off + blockIdx.x * 256 + t;
        int ec = e < N_EDGES ? e : N_EDGES - 1;
        int sv = src[ec];
        const v8h* xr = (const v8h*)(x16 + (size_t)sv * DIM);
        #pragma unroll
        for (int u = 0; u < 4; ++u) {
            v8h v = xr[u];
            #pragma unroll
            for (int j = 0; j < 8; ++j)
                xs[(u * 8 + j) * 256 + t] = v[j];
        }
    }
    __syncthreads();

    v4f acc[4][2];
    #pragma unroll
    for (int mt = 0; mt < 4; ++mt)
        #pragma unroll
        for (int ng = 0; ng < 2; ++ng) { v4f z = {0.f, 0.f, 0.f, 0.f}; acc[mt][ng] = z; }

    _Float16 xsc[4];

    for (int s = 0; s < NSTAGES - 1; ++s) {
        {
            const char* gp = (const char*)(w2f + (size_t)(s + 1) * CH * 1024);
            char* lp = (char*)&bst[(s + 1) & 1][0];
            #pragma unroll
            for (int it = 0; it < 4; ++it)
                gld_lds16(gp + it * 4096 + t * 16, lp + it * 4096 + t * 16);
        }
        const _Float16* bb = &bst[s & 1][0];
        #pragma unroll
        for (int ktl = 0; ktl < CH; ++ktl) {
            int kt = s * CH + ktl;
            v8h b0 = *(const v8h*)(bb + ktl * 1024 + lane * 8);
            v8h b1 = *(const v8h*)(bb + ktl * 1024 + 512 + lane * 8);
            if ((kt & 3) == 0) {
                int i = kt >> 2;
                #pragma unroll
                for (int mt = 0; mt < 4; ++mt)
                    xsc[mt] = xs[i * 256 + wbase + mt * 16 + lr];
            }
            int kc = kt & 3;
            #pragma unroll
            for (int mt = 0; mt < 4; ++mt) {
                v8h a = hwr[mt][kc] * xsc[mt];
                acc[mt][0] = __builtin_amdgcn_mfma_f32_16x16x32_f16(a, b0, acc[mt][0], 0, 0, 0);
                acc[mt][1] = __builtin_amdgcn_mfma_f32_16x16x32_f16(a, b1, acc[mt][1], 0, 0, 0);
            }
        }
        __syncthreads();
    }
    {
        const _Float16* bb = &bst[0][0];
        v8h b0 = *(const v8h*)(bb + lane * 8);
        v8h b1 = *(const v8h*)(bb + 512 + lane * 8);
        #pragma unroll
        for (int mt = 0; mt < 4; ++mt) {
            v8h a;
            #pragma unroll
            for (int j = 0; j < 8; ++j)
                a[j] = xs[(q * 8 + j) * 256 + wbase + mt * 16 + lr];
            acc[mt][0] = __builtin_amdgcn_mfma_f32_16x16x32_f16(a, b0, acc[mt][0], 0, 0, 0);
            acc[mt][1] = __builtin_amdgcn_mfma_f32_16x16x32_f16(a, b1, acc[mt][1], 0, 0, 0);
        }
    }

    int E0 = e_off + blockIdx.x * 256 + wbase;
    #pragma unroll
    for (int mt = 0; mt < 4; ++mt) {
        #pragma unroll
        for (int r = 0; r < 4; ++r) {
            int e = E0 + mt * 16 + q * 4 + r;
            if (e < N_EDGES) {
                int dv = dst[e];
                float* sp = sbuf + (size_t)dv * DIM;
                atomicAdd(sp + lr,      acc[mt][0][r]);
                atomicAdd(sp + 16 + lr, acc[mt][1][r]);
            }
        }
    }
}

// -------- MFMA GRU: 128 nodes/block, prepacked fp16 weights, zeroes sbuf --------
__global__ __launch_bounds__(256) void gru_kernel(
    float* __restrict__ s, const float* __restrict__ cnt,
    const float* __restrict__ cb, const _Float16* __restrict__ gw,
    const float* __restrict__ bih, const float* __restrict__ bhh,
    _Float16* __restrict__ h16, float* __restrict__ hout, int last) {
    __shared__ _Float16 wi_l[4096], wh_l[4096];
    __shared__ float bi_l[96], bh_l[96];
    __shared__ _Float16 m_l[128 * 32], h_l[128 * 32];
    int t = threadIdx.x;

    {
        const char* gp = (const char*)gw;
        gld_lds16(gp + t * 16,         (char*)wi_l + t * 16);
        gld_lds16(gp + 4096 + t * 16,  (char*)wi_l + 4096 + t * 16);
        gld_lds16(gp + 8192 + t * 16,  (char*)wh_l + t * 16);
        gld_lds16(gp + 12288 + t * 16, (char*)wh_l + 4096 + t * 16);
    }
    if (t < 96) { bi_l[t] = bih[t]; bh_l[t] = bhh[t]; }

    // stage m/h16; zero sbuf. cb read from GLOBAL (LDS copy would race pre-barrier)
    {
        int node_l = t >> 1, part = t & 1;
        int n = blockIdx.x * 128 + node_l;
        int nc = n < N_NODES ? n : N_NODES - 1;
        float c = cnt[nc];
        float rc = 1.f / (c > 1.f ? c : 1.f);
        float4* s4 = (float4*)(s + (size_t)nc * DIM + part * 16);
        const float* cbp = cb + part * 16;
        #pragma unroll
        for (int u = 0; u < 2; ++u) {
            float4 sa = s4[u * 2], sb = s4[u * 2 + 1];
            v8h mv;
            mv[0] = (_Float16)fmaxf(sa.x * rc + cbp[u * 8 + 0], 0.f);
            mv[1] = (_Float16)fmaxf(sa.y * rc + cbp[u * 8 + 1], 0.f);
            mv[2] = (_Float16)fmaxf(sa.z * rc + cbp[u * 8 + 2], 0.f);
            mv[3] = (_Float16)fmaxf(sa.w * rc + cbp[u * 8 + 3], 0.f);
            mv[4] = (_Float16)fmaxf(sb.x * rc + cbp[u * 8 + 4], 0.f);
            mv[5] = (_Float16)fmaxf(sb.y * rc + cbp[u * 8 + 5], 0.f);
            mv[6] = (_Float16)fmaxf(sb.z * rc + cbp[u * 8 + 6], 0.f);
            mv[7] = (_Float16)fmaxf(sb.w * rc + cbp[u * 8 + 7], 0.f);
            *(v8h*)&m_l[node_l * 32 + part * 16 + u * 8] = mv;
        }
        if (n < N_NODES) {
            float4 z4 = {0.f, 0.f, 0.f, 0.f};
            s4[0] = z4; s4[1] = z4; s4[2] = z4; s4[3] = z4;
        }
        const v8h* h8 = (const v8h*)(h16 + (size_t)nc * DIM + part * 16);
        *(v8h*)&h_l[node_l * 32 + part * 16]     = h8[0];
        *(v8h*)&h_l[node_l * 32 + part * 16 + 8] = h8[1];
    }

    __syncthreads();

    int w = t >> 6, lane = t & 63, lr = lane & 15, q = lane >> 4;

    v8h bi6[6], bh6[6];
    #pragma unroll
    for (int nt = 0; nt < 6; ++nt) {
        bi6[nt] = *(const v8h*)&wi_l[(nt * 16 + lr) * 40 + q * 8];
        bh6[nt] = *(const v8h*)&wh_l[(nt * 16 + lr) * 40 + q * 8];
    }

    #pragma unroll
    for (int p = 0; p < 2; ++p) {
        int tb = w * 32 + p * 16;
        v4f ai[6], ah[6];
        #pragma unroll
        for (int nt = 0; nt < 6; ++nt) {
            float bii = bi_l[nt * 16 + lr], bhi = bh_l[nt * 16 + lr];
            v4f ci = {bii, bii, bii, bii}; ai[nt] = ci;
            v4f chh = {bhi, bhi, bhi, bhi}; ah[nt] = chh;
        }
        v8h ma = *(const v8h*)&m_l[(tb + lr) * 32 + q * 8];
        v8h ha = *(const v8h*)&h_l[(tb + lr) * 32 + q * 8];
        #pragma unroll
        for (int nt = 0; nt < 6; ++nt) {
            ai[nt] = __builtin_amdgcn_mfma_f32_16x16x32_f16(ma, bi6[nt], ai[nt], 0, 0, 0);
            ah[nt] = __builtin_amdgcn_mfma_f32_16x16x32_f16(ha, bh6[nt], ah[nt], 0, 0, 0);
        }
        int nb = blockIdx.x * 128 + tb + q * 4;
        #pragma unroll
        for (int g = 0; g < 2; ++g) {
            int o = g * 16 + lr;
            #pragma unroll
            for (int r = 0; r < 4; ++r) {
                int n2 = nb + r;
                if (n2 < N_NODES) {
                    float rg = 1.f / (1.f + expf(-(ai[g][r]     + ah[g][r])));
                    float zg = 1.f / (1.f + expf(-(ai[2 + g][r] + ah[2 + g][r])));
                    float ng = tanhf(ai[4 + g][r] + rg * ah[4 + g][r]);
                    float hold = (float)h_l[(tb + q * 4 + r) * 32 + o];
                    float hn = (1.f - zg) * ng + zg * hold;
                    h16[(size_t)n2 * DIM + o] = (_Float16)hn;
                    if (last) hout[(size_t)n2 * DIM + o] = hn;
                }
            }
        }
    }
}

// -------- fused Set2Set: LSTM + online-softmax attention, 1 wave/graph, 2 nodes/iter --------
__global__ __launch_bounds__(256) void s2s_kernel(
    const float* __restrict__ wih, const float* __restrict__ whh,
    const float* __restrict__ bih, const float* __restrict__ bhh,
    float* __restrict__ h, float* __restrict__ c,
    float* __restrict__ rnum, float* __restrict__ denom,
    const float* __restrict__ x, const int* __restrict__ gstart,
    float* __restrict__ outp, int first, int wout) {
    __shared__ float wA[128 * 33], wB[128 * 33], bl[128];
    int t = threadIdx.x;
    for (int i = t; i < 128 * 32; i += 256) {
        int r = i >> 5, cc = i & 31;
        wA[r * 33 + cc] = wih[r * 64 + cc] + whh[r * 32 + cc];
        wB[r * 33 + cc] = wih[r * 64 + 32 + cc];
    }
    if (t < 128) bl[t] = bih[t] + bhh[t];
    __syncthreads();
    int gl = t >> 6, half = (t >> 5) & 1, o = t & 31;
    int b = blockIdx.x * 4 + gl;
    if (b >= N_GRAPHS) return;

    // LSTM (computed redundantly by both halves — identical inputs)
    float hq = 0.f, rr = 0.f, cv = 0.f;
    if (!first) {
        hq = h[b * DIM + o];
        float d = denom[b];
        rr = d > 0.f ? rnum[b * DIM + o] / d : 0.f;
        cv = c[b * DIM + o];
    }
    float gi = bl[o], gf = bl[32 + o], gg = bl[64 + o], go = bl[96 + o];
    #pragma unroll
    for (int i = 0; i < 32; ++i) {
        float qv = __shfl(hq, i, 32);
        float rv = __shfl(rr, i, 32);
        gi += qv * wA[o * 33 + i]        + rv * wB[o * 33 + i];
        gf += qv * wA[(32 + o) * 33 + i] + rv * wB[(32 + o) * 33 + i];
        gg += qv * wA[(64 + o) * 33 + i] + rv * wB[(64 + o) * 33 + i];
        go += qv * wA[(96 + o) * 33 + i] + rv * wB[(96 + o) * 33 + i];
    }
    float si = 1.f / (1.f + expf(-gi));
    float sf = 1.f / (1.f + expf(-gf));
    float so = 1.f / (1.f + expf(-go));
    float cn = sf * cv + si * tanhf(gg);
    float qo = so * tanhf(cn);
    if (half == 0) {
        c[b * DIM + o] = cn;
        h[b * DIM + o] = qo;
    }

    // attention: halves take alternating nodes, merge online-softmax states at end
    int n0 = gstart[b], n1 = gstart[b + 1];
    float m0 = -3.0e38f, s = 0.f, r = 0.f;
    for (int n = n0 + half; n < n1; n += 2) {
        float xo = x[(size_t)n * DIM + o];
        float e = xo * qo;
        #pragma unroll
        for (int mm = 16; mm >= 1; mm >>= 1) e += __shfl_xor(e, mm, 32);
        float nm = fmaxf(m0, e);
        float sc = expf(m0 - nm);
        float ex = expf(e - nm);
        s = s * sc + ex;
        r = r * sc + ex * xo;
        m0 = nm;
    }
    // cross-half merge (width 64)
    float vm = __shfl_xor(m0, 32);
    float vs = __shfl_xor(s, 32);
    float vr = __shfl_xor(r, 32);
    float nm = fmaxf(m0, vm);
    float sc0 = expf(m0 - nm), sc1 = expf(vm - nm);
    s = s * sc0 + vs * sc1;
    r = r * sc0 + vr * sc1;

    if (half == 0) {
        rnum[b * DIM + o] = r;
        if (o == 0) denom[b] = s;
        if (wout) {
            outp[b * 64 + o]      = qo;
            outp[b * 64 + 32 + o] = s > 0.f ? r / s : 0.f;
        }
    }
}

extern "C" void kernel_launch(void* const* d_in, const int* in_sizes, int n_in,
                              void* d_out, int out_size, void* d_ws, size_t ws_size,
                              hipStream_t stream) {
    const float* nf   = (const float*)d_in[0];
    const float* ef   = (const float*)d_in[1];
    const float* l0w  = (const float*)d_in[2];
    const float* l0b  = (const float*)d_in[3];
    const float* w1   = (const float*)d_in[4];
    const float* b1   = (const float*)d_in[5];
    const float* w2   = (const float*)d_in[6];
    const float* b2   = (const float*)d_in[7];
    const float* cb   = (const float*)d_in[8];
    const float* gwih = (const float*)d_in[9];
    const float* gwhh = (const float*)d_in[10];
    const float* gbih = (const float*)d_in[11];
    const float* gbhh = (const float*)d_in[12];
    const float* lwih = (const float*)d_in[13];
    const float* lwhh = (const float*)d_in[14];
    const float* lbih = (const float*)d_in[15];
    const float* lbhh = (const float*)d_in[16];
    const int*   eidx = (const int*)d_in[17];
    const int*   gidx = (const int*)d_in[18];
    const int* src = eidx;
    const int* dst = eidx + N_EDGES;
    float* out = (float*)d_out;
    float* h   = out + (size_t)N_GRAPHS * 64;   // fp32 node state (final) in d_out tail

    char* ws = (char*)d_ws;
    size_t off = 0;
    auto alloc = [&](size_t bytes) -> void* {
        void* p = ws + off;
        off = (off + bytes + 255) & ~(size_t)255;
        return p;
    };
    float* sbuf  = (float*)alloc((size_t)N_NODES * DIM * 4);   // 12.8 MB
    float* cnt   = (float*)alloc((size_t)N_NODES * 4);
    _Float16* h16 = (_Float16*)alloc((size_t)N_NODES * DIM * 2); // 6.4 MB
    float* hs    = (float*)alloc((size_t)N_GRAPHS * DIM * 4);
    float* cs    = (float*)alloc((size_t)N_GRAPHS * DIM * 4);
    float* rnum  = (float*)alloc((size_t)N_GRAPHS * DIM * 4);
    float* denom = (float*)alloc((size_t)N_GRAPHS * 4);
    int*   gstart = (int*)alloc((size_t)(N_GRAPHS + 1) * 4);
    _Float16* w2f  = (_Float16*)alloc((size_t)W2F_HALFS * 2);  // 272 KB
    _Float16* gw   = (_Float16*)alloc((size_t)16384);          // prepacked GRU weights
    size_t fixed = off;
    size_t avail = ws_size > fixed ? ws_size - fixed : 0;

    auto need = [&](int nc) -> size_t {
        int cbk = (MSG_BLOCKS + nc - 1) / nc;
        return (size_t)cbk * 16 * 4096;   // 16 tiles/block * 4 KB/tile
    };
    int nchunk = 1;
    while (nchunk < 64 && need(nchunk) > avail) nchunk <<= 1;
    int chunk_blocks = (MSG_BLOCKS + nchunk - 1) / nchunk;
    _Float16* hwf = (_Float16*)alloc(need(nchunk));

    // ---- prologue (3 dispatches, no memsets) ----
    lin0_kernel<<<dim3((N_NODES + 31) / 32), dim3(256), 0, stream>>>(
        nf, l0w, l0b, h16, cnt, sbuf);
    aux_kernel<<<dim3(CNT_BLOCKS + OFFS_BLOCKS + GRUW_BLOCKS + W2F_BLOCKS), dim3(256), 0, stream>>>(
        dst, cnt, gidx, gstart, gwih, gwhh, gw, w2, b2, w2f);
    if (nchunk == 1) {
        hw_kernel<<<dim3((MSG_BLOCKS * 256 + 63) / 64), dim3(256), 0, stream>>>(ef, w1, b1, hwf, 0);
    }

    // ---- 3 message-passing + GRU iterations ----
    for (int it = 0; it < 3; ++it) {
        for (int cix = 0; cix < nchunk; ++cix) {
            int bstart = cix * chunk_blocks;
            int bc = MSG_BLOCKS - bstart;
            if (bc <= 0) break;
            if (bc > chunk_blocks) bc = chunk_blocks;
            int e_off = bstart * 256;
            if (nchunk > 1)
                hw_kernel<<<dim3(bc * 4), dim3(256), 0, stream>>>(ef, w1, b1, hwf, e_off);
            msg_kernel<<<dim3(bc), dim3(256), 0, stream>>>(hwf, w2f, h16, src, dst, sbuf, e_off);
        }
        gru_kernel<<<dim3((N_NODES + 127) / 128), dim3(256), 0, stream>>>(
            sbuf, cnt, cb, gw, gbih, gbhh, h16, h, it == 2 ? 1 : 0);
    }

    // ---- Set2Set: 3 fused LSTM+attention steps (1 wave per graph) ----
    for (int st = 0; st < 3; ++st) {
        s2s_kernel<<<dim3((N_GRAPHS + 3) / 4), dim3(256), 0, stream>>>(
            lwih, lwhh, lbih, lbhh, hs, cs, rnum, denom, h, gstart, out,
            st == 0 ? 1 : 0, st == 2 ? 1 : 0);
    }
}

// Round 12
// 587.048 us; speedup vs baseline: 1.0348x; 1.0348x over previous
//
#include <hip/hip_runtime.h>
#include <stdint.h>

#define N_NODES  100000
#define N_EDGES  250000
#define N_GRAPHS 2000
#define F_IN     75
#define DIM      32
#define H1       128

#define MSG_BLOCKS 977           // ceil(250000/256), 256 edges per msg block
#define CH        8              // kt per LDS stage (16 KB)
#define NSTAGES   17
#define KT_PAD    (CH * NSTAGES) // 136, padded with zeros
#define W2F_HALFS (KT_PAD * 1024)

#define CNT_BLOCKS  ((N_EDGES + 255) / 256)     // 977
#define OFFS_BLOCKS ((N_NODES + 255) / 256)     // 391
#define GRUW_BLOCKS 32                          // 2x4096 halves / 256
#define W2F_BLOCKS  ((W2F_HALFS + 255) / 256)   // 544

typedef _Float16 v8h __attribute__((ext_vector_type(8)));
typedef float    v4f __attribute__((ext_vector_type(4)));

__device__ __forceinline__ void gld_lds16(const void* g, void* l) {
    __builtin_amdgcn_global_load_lds(
        (const __attribute__((address_space(1))) unsigned int*)g,
        (__attribute__((address_space(3))) unsigned int*)l, 16, 0, 0);
}

// -------- lin0: h16 = relu(nf @ W.T + b); also zeroes cnt + sbuf (replaces memsets) --------
__global__ __launch_bounds__(256) void lin0_kernel(
    const float* __restrict__ nf, const float* __restrict__ w,
    const float* __restrict__ b, _Float16* __restrict__ h16,
    float* __restrict__ cnt, float* __restrict__ sbuf) {
    __shared__ float wl[DIM * F_IN];
    __shared__ float bl[DIM];
    int t = threadIdx.x;
    for (int i = t; i < DIM * F_IN; i += 256) wl[i] = w[i];
    if (t < DIM) bl[t] = b[t];
    __syncthreads();
    int nl = t >> 5, o = t & 31;
    #pragma unroll
    for (int p = 0; p < 4; ++p) {
        int n = blockIdx.x * 32 + p * 8 + nl;
        if (n >= N_NODES) continue;
        const float* row = nf + (size_t)n * F_IN;
        float acc = bl[o];
        #pragma unroll
        for (int i = 0; i < F_IN; ++i) acc += row[i] * wl[o * F_IN + i];
        h16[(size_t)n * DIM + o] = (_Float16)fmaxf(acc, 0.f);
    }
    if (t < 32) {
        int n = blockIdx.x * 32 + t;
        if (n < N_NODES) cnt[n] = 0.f;
    }
    #pragma unroll
    for (int p = 0; p < 4; ++p) {
        size_t idx = (size_t)blockIdx.x * 1024 + p * 256 + t;
        if (idx < (size_t)N_NODES * DIM) sbuf[idx] = 0.f;
    }
}

// -------- aux: cnt atomics + graph offsets + GRU weight prepack + W2t fp16 table --------
__global__ __launch_bounds__(256) void aux_kernel(
    const int* __restrict__ dst, float* __restrict__ cnt,
    const int* __restrict__ gidx, int* __restrict__ gstart,
    const float* __restrict__ wih, const float* __restrict__ whh,
    _Float16* __restrict__ gw,
    const float* __restrict__ w2, const float* __restrict__ b2,
    _Float16* __restrict__ w2f) {
    int t = threadIdx.x;
    unsigned bx = blockIdx.x;
    if (bx < CNT_BLOCKS) {
        int e = bx * 256 + t;
        if (e < N_EDGES) atomicAdd(&cnt[dst[e]], 1.0f);
    } else if (bx < CNT_BLOCKS + OFFS_BLOCKS) {
        int n = (bx - CNT_BLOCKS) * 256 + t;
        if (n >= N_NODES) return;
        int b = gidx[n];
        if (n == 0) {
            for (int bb = 0; bb <= b; ++bb) gstart[bb] = 0;
        } else {
            int a = gidx[n - 1];
            for (int bb = a + 1; bb <= b; ++bb) gstart[bb] = n;
        }
        if (n == N_NODES - 1) {
            for (int bb = b + 1; bb <= N_GRAPHS; ++bb) gstart[bb] = N_NODES;
        }
    } else if (bx < CNT_BLOCKS + OFFS_BLOCKS + GRUW_BLOCKS) {
        int id = (bx - CNT_BLOCKS - OFFS_BLOCKS) * 256 + t;
        if (id >= 8192) return;
        int im = id & 4095;
        int r = im / 40, c = im - r * 40;
        float val = 0.f;
        if (r < 96 && c < 32) val = (id < 4096) ? wih[r * 32 + c] : whh[r * 32 + c];
        gw[id] = (_Float16)val;
    } else {
        int id = (bx - CNT_BLOCKS - OFFS_BLOCKS - GRUW_BLOCKS) * 256 + t;
        if (id >= W2F_HALFS) return;
        int j    = id & 7;
        int lane = (id >> 3) & 63;
        int ng   = (id >> 9) & 1;
        int kt   = id >> 10;
        int lr = lane & 15, q = lane >> 4;
        int c = kt * 32 + q * 8 + j;
        int o = ng * 16 + lr;
        float val = 0.f;
        if (c < 4096)      val = w2[((c >> 7) * 32 + o) * H1 + (c & 127)];
        else if (c < 4128) val = b2[(c - 4096) * 32 + o];
        w2f[id] = (_Float16)val;
    }
}

// -------- edge hidden hw = relu(ef @ W1.T + b1), fp16 FRAG-MAJOR, 32 edges/block (R10) --------
__global__ __launch_bounds__(256) void hw_kernel(
    const float* __restrict__ ef, const float* __restrict__ w1,
    const float* __restrict__ b1, _Float16* __restrict__ hwf,
    int e_off) {
    __shared__ float wl[H1 * 11];
    __shared__ float bl[H1];
    int t = threadIdx.x;
    for (int i = t; i < H1 * 11; i += 256) wl[i] = w1[i];
    if (t < H1) bl[t] = b1[t];
    __syncthreads();
    int k = t & 127;
    #pragma unroll
    for (int p = 0; p < 16; ++p) {
        int le = blockIdx.x * 32 + p * 2 + (t >> 7);
        int e  = e_off + le;
        float acc = 0.f;
        if (e < N_EDGES) {
            const float* row = ef + (size_t)e * 11;
            acc = bl[k];
            #pragma unroll
            for (int i = 0; i < 11; ++i) acc += row[i] * wl[k * 11 + i];
            acc = fmaxf(acc, 0.f);
        }
        size_t addr = (size_t)(le >> 4) * 2048 + (k >> 3) * 128 + (le & 15) * 8 + (k & 7);
        hwf[addr] = (_Float16)acc;
    }
}

// -------- fused message GEMM: msg = (x[src] (x) hw) @ W2t, LDS-staged B --------
__global__ __launch_bounds__(256) void msg_kernel(
    const _Float16* __restrict__ hwf, const _Float16* __restrict__ w2f,
    const _Float16* __restrict__ x16, const int* __restrict__ src,
    const int* __restrict__ dst, float* __restrict__ sbuf, int e_off) {
    __shared__ _Float16 xs[32 * 256];        // 16 KB: xs[i][e_loc]
    __shared__ _Float16 bst[2][CH * 1024];   // 2 x 16 KB B stages

    int t = threadIdx.x;
    int w = t >> 6, lane = t & 63, lr = lane & 15, q = lane >> 4;
    int wbase = w * 64;

    {
        const char* gp = (const char*)w2f;
        char* lp = (char*)&bst[0][0];
        #pragma unroll
        for (int it = 0; it < 4; ++it)
            gld_lds16(gp + it * 4096 + t * 16, lp + it * 4096 + t * 16);
    }

    v8h hwr[4][4];
    {
        const v8h* hv = (const v8h*)hwf;
        int T0 = blockIdx.x * 16 + w * 4;
        #pragma unroll
        for (int mt = 0; mt < 4; ++mt)
            #pragma unroll
            for (int kc = 0; kc < 4; ++kc)
                hwr[mt][kc] = hv[(size_t)(T0 + mt) * 256 + (kc * 4 + q) * 16 + lr];
    }

    {
        int e = e_off + blockIdx.x * 256 + t;
        int ec = e < N_EDGES ? e : N_EDGES - 1;
        int sv = src[ec];
        const v8h* xr = (const v8h*)(x16 + (size_t)sv * DIM);
        #pragma unroll
        for (int u = 0; u < 4; ++u) {
            v8h v = xr[u];
            #pragma unroll
            for (int j = 0; j < 8; ++j)
                xs[(u * 8 + j) * 256 + t] = v[j];
        }
    }
    __syncthreads();

    v4f acc[4][2];
    #pragma unroll
    for (int mt = 0; mt < 4; ++mt)
        #pragma unroll
        for (int ng = 0; ng < 2; ++ng) { v4f z = {0.f, 0.f, 0.f, 0.f}; acc[mt][ng] = z; }

    _Float16 xsc[4];

    for (int s = 0; s < NSTAGES - 1; ++s) {
        {
            const char* gp = (const char*)(w2f + (size_t)(s + 1) * CH * 1024);
            char* lp = (char*)&bst[(s + 1) & 1][0];
            #pragma unroll
            for (int it = 0; it < 4; ++it)
                gld_lds16(gp + it * 4096 + t * 16, lp + it * 4096 + t * 16);
        }
        const _Float16* bb = &bst[s & 1][0];
        #pragma unroll
        for (int ktl = 0; ktl < CH; ++ktl) {
            int kt = s * CH + ktl;
            v8h b0 = *(const v8h*)(bb + ktl * 1024 + lane * 8);
            v8h b1 = *(const v8h*)(bb + ktl * 1024 + 512 + lane * 8);
            if ((kt & 3) == 0) {
                int i = kt >> 2;
                #pragma unroll
                for (int mt = 0; mt < 4; ++mt)
                    xsc[mt] = xs[i * 256 + wbase + mt * 16 + lr];
            }
            int kc = kt & 3;
            #pragma unroll
            for (int mt = 0; mt < 4; ++mt) {
                v8h a = hwr[mt][kc] * xsc[mt];
                acc[mt][0] = __builtin_amdgcn_mfma_f32_16x16x32_f16(a, b0, acc[mt][0], 0, 0, 0);
                acc[mt][1] = __builtin_amdgcn_mfma_f32_16x16x32_f16(a, b1, acc[mt][1], 0, 0, 0);
            }
        }
        __syncthreads();
    }
    {
        const _Float16* bb = &bst[0][0];
        v8h b0 = *(const v8h*)(bb + lane * 8);
        v8h b1 = *(const v8h*)(bb + 512 + lane * 8);
        #pragma unroll
        for (int mt = 0; mt < 4; ++mt) {
            v8h a;
            #pragma unroll
            for (int j = 0; j < 8; ++j)
                a[j] = xs[(q * 8 + j) * 256 + wbase + mt * 16 + lr];
            acc[mt][0] = __builtin_amdgcn_mfma_f32_16x16x32_f16(a, b0, acc[mt][0], 0, 0, 0);
            acc[mt][1] = __builtin_amdgcn_mfma_f32_16x16x32_f16(a, b1, acc[mt][1], 0, 0, 0);
        }
    }

    int E0 = e_off + blockIdx.x * 256 + wbase;
    #pragma unroll
    for (int mt = 0; mt < 4; ++mt) {
        #pragma unroll
        for (int r = 0; r < 4; ++r) {
            int e = E0 + mt * 16 + q * 4 + r;
            if (e < N_EDGES) {
                int dv = dst[e];
                float* sp = sbuf + (size_t)dv * DIM;
                atomicAdd(sp + lr,      acc[mt][0][r]);
                atomicAdd(sp + 16 + lr, acc[mt][1][r]);
            }
        }
    }
}

// -------- MFMA GRU: 128 nodes/block, prepacked fp16 weights, zeroes sbuf --------
__global__ __launch_bounds__(256) void gru_kernel(
    float* __restrict__ s, const float* __restrict__ cnt,
    const float* __restrict__ cb, const _Float16* __restrict__ gw,
    const float* __restrict__ bih, const float* __restrict__ bhh,
    _Float16* __restrict__ h16, float* __restrict__ hout, int last) {
    __shared__ _Float16 wi_l[4096], wh_l[4096];
    __shared__ float bi_l[96], bh_l[96];
    __shared__ _Float16 m_l[128 * 32], h_l[128 * 32];
    int t = threadIdx.x;

    {
        const char* gp = (const char*)gw;
        gld_lds16(gp + t * 16,         (char*)wi_l + t * 16);
        gld_lds16(gp + 4096 + t * 16,  (char*)wi_l + 4096 + t * 16);
        gld_lds16(gp + 8192 + t * 16,  (char*)wh_l + t * 16);
        gld_lds16(gp + 12288 + t * 16, (char*)wh_l + 4096 + t * 16);
    }
    if (t < 96) { bi_l[t] = bih[t]; bh_l[t] = bhh[t]; }

    // stage m/h16; zero sbuf. cb read from GLOBAL (LDS copy would race pre-barrier)
    {
        int node_l = t >> 1, part = t & 1;
        int n = blockIdx.x * 128 + node_l;
        int nc = n < N_NODES ? n : N_NODES - 1;
        float c = cnt[nc];
        float rc = 1.f / (c > 1.f ? c : 1.f);
        float4* s4 = (float4*)(s + (size_t)nc * DIM + part * 16);
        const float* cbp = cb + part * 16;
        #pragma unroll
        for (int u = 0; u < 2; ++u) {
            float4 sa = s4[u * 2], sb = s4[u * 2 + 1];
            v8h mv;
            mv[0] = (_Float16)fmaxf(sa.x * rc + cbp[u * 8 + 0], 0.f);
            mv[1] = (_Float16)fmaxf(sa.y * rc + cbp[u * 8 + 1], 0.f);
            mv[2] = (_Float16)fmaxf(sa.z * rc + cbp[u * 8 + 2], 0.f);
            mv[3] = (_Float16)fmaxf(sa.w * rc + cbp[u * 8 + 3], 0.f);
            mv[4] = (_Float16)fmaxf(sb.x * rc + cbp[u * 8 + 4], 0.f);
            mv[5] = (_Float16)fmaxf(sb.y * rc + cbp[u * 8 + 5], 0.f);
            mv[6] = (_Float16)fmaxf(sb.z * rc + cbp[u * 8 + 6], 0.f);
            mv[7] = (_Float16)fmaxf(sb.w * rc + cbp[u * 8 + 7], 0.f);
            *(v8h*)&m_l[node_l * 32 + part * 16 + u * 8] = mv;
        }
        if (n < N_NODES) {
            float4 z4 = {0.f, 0.f, 0.f, 0.f};
            s4[0] = z4; s4[1] = z4; s4[2] = z4; s4[3] = z4;
        }
        const v8h* h8 = (const v8h*)(h16 + (size_t)nc * DIM + part * 16);
        *(v8h*)&h_l[node_l * 32 + part * 16]     = h8[0];
        *(v8h*)&h_l[node_l * 32 + part * 16 + 8] = h8[1];
    }

    __syncthreads();

    int w = t >> 6, lane = t & 63, lr = lane & 15, q = lane >> 4;

    v8h bi6[6], bh6[6];
    #pragma unroll
    for (int nt = 0; nt < 6; ++nt) {
        bi6[nt] = *(const v8h*)&wi_l[(nt * 16 + lr) * 40 + q * 8];
        bh6[nt] = *(const v8h*)&wh_l[(nt * 16 + lr) * 40 + q * 8];
    }

    #pragma unroll
    for (int p = 0; p < 2; ++p) {
        int tb = w * 32 + p * 16;
        v4f ai[6], ah[6];
        #pragma unroll
        for (int nt = 0; nt < 6; ++nt) {
            float bii = bi_l[nt * 16 + lr], bhi = bh_l[nt * 16 + lr];
            v4f ci = {bii, bii, bii, bii}; ai[nt] = ci;
            v4f chh = {bhi, bhi, bhi, bhi}; ah[nt] = chh;
        }
        v8h ma = *(const v8h*)&m_l[(tb + lr) * 32 + q * 8];
        v8h ha = *(const v8h*)&h_l[(tb + lr) * 32 + q * 8];
        #pragma unroll
        for (int nt = 0; nt < 6; ++nt) {
            ai[nt] = __builtin_amdgcn_mfma_f32_16x16x32_f16(ma, bi6[nt], ai[nt], 0, 0, 0);
            ah[nt] = __builtin_amdgcn_mfma_f32_16x16x32_f16(ha, bh6[nt], ah[nt], 0, 0, 0);
        }
        int nb = blockIdx.x * 128 + tb + q * 4;
        #pragma unroll
        for (int g = 0; g < 2; ++g) {
            int o = g * 16 + lr;
            #pragma unroll
            for (int r = 0; r < 4; ++r) {
                int n2 = nb + r;
                if (n2 < N_NODES) {
                    float rg = 1.f / (1.f + expf(-(ai[g][r]     + ah[g][r])));
                    float zg = 1.f / (1.f + expf(-(ai[2 + g][r] + ah[2 + g][r])));
                    float ng = tanhf(ai[4 + g][r] + rg * ah[4 + g][r]);
                    float hold = (float)h_l[(tb + q * 4 + r) * 32 + o];
                    float hn = (1.f - zg) * ng + zg * hold;
                    h16[(size_t)n2 * DIM + o] = (_Float16)hn;
                    if (last) hout[(size_t)n2 * DIM + o] = hn;
                }
            }
        }
    }
}

// -------- Set2Set, ALL 3 steps in one kernel: per-graph state lives in registers --------
// block = 8 graphs (32-lane group each); weights staged once; no hs/cs/rnum/denom buffers
__global__ __launch_bounds__(256) void s2s_kernel(
    const float* __restrict__ wih, const float* __restrict__ whh,
    const float* __restrict__ bih, const float* __restrict__ bhh,
    const float* __restrict__ x, const int* __restrict__ gstart,
    float* __restrict__ outp) {
    __shared__ float wA[128 * 33], wB[128 * 33], bl[128];
    int t = threadIdx.x;
    for (int i = t; i < 128 * 32; i += 256) {
        int r = i >> 5, cc = i & 31;
        wA[r * 33 + cc] = wih[r * 64 + cc] + whh[r * 32 + cc];
        wB[r * 33 + cc] = wih[r * 64 + 32 + cc];
    }
    if (t < 128) bl[t] = bih[t] + bhh[t];
    __syncthreads();
    int gl = t >> 5, o = t & 31;
    int b = blockIdx.x * 8 + gl;
    if (b >= N_GRAPHS) return;
    int n0 = gstart[b], n1 = gstart[b + 1];

    float hq = 0.f, rr = 0.f, cv = 0.f;   // q, r (normalized), c — all in registers
    #pragma unroll 1
    for (int st = 0; st < 3; ++st) {
        // LSTM cell on q_star = [hq, rr]
        float gi = bl[o], gf = bl[32 + o], gg = bl[64 + o], go = bl[96 + o];
        #pragma unroll
        for (int i = 0; i < 32; ++i) {
            float qv = __shfl(hq, i, 32);
            float rv = __shfl(rr, i, 32);
            gi += qv * wA[o * 33 + i]        + rv * wB[o * 33 + i];
            gf += qv * wA[(32 + o) * 33 + i] + rv * wB[(32 + o) * 33 + i];
            gg += qv * wA[(64 + o) * 33 + i] + rv * wB[(64 + o) * 33 + i];
            go += qv * wA[(96 + o) * 33 + i] + rv * wB[(96 + o) * 33 + i];
        }
        float si = 1.f / (1.f + expf(-gi));
        float sf = 1.f / (1.f + expf(-gf));
        float so = 1.f / (1.f + expf(-go));
        cv = sf * cv + si * tanhf(gg);
        hq = so * tanhf(cv);

        // attention (online softmax, no atomics)
        float m0 = -3.0e38f, s = 0.f, r = 0.f;
        for (int n = n0; n < n1; ++n) {
            float xo = x[(size_t)n * DIM + o];
            float e = xo * hq;
            #pragma unroll
            for (int mm = 16; mm >= 1; mm >>= 1) e += __shfl_xor(e, mm, 32);
            float nm = fmaxf(m0, e);
            float sc = expf(m0 - nm);
            float ex = expf(e - nm);
            s = s * sc + ex;
            r = r * sc + ex * xo;
            m0 = nm;
        }
        rr = s > 0.f ? r / s : 0.f;
    }
    outp[b * 64 + o]      = hq;
    outp[b * 64 + 32 + o] = rr;
}

extern "C" void kernel_launch(void* const* d_in, const int* in_sizes, int n_in,
                              void* d_out, int out_size, void* d_ws, size_t ws_size,
                              hipStream_t stream) {
    const float* nf   = (const float*)d_in[0];
    const float* ef   = (const float*)d_in[1];
    const float* l0w  = (const float*)d_in[2];
    const float* l0b  = (const float*)d_in[3];
    const float* w1   = (const float*)d_in[4];
    const float* b1   = (const float*)d_in[5];
    const float* w2   = (const float*)d_in[6];
    const float* b2   = (const float*)d_in[7];
    const float* cb   = (const float*)d_in[8];
    const float* gwih = (const float*)d_in[9];
    const float* gwhh = (const float*)d_in[10];
    const float* gbih = (const float*)d_in[11];
    const float* gbhh = (const float*)d_in[12];
    const float* lwih = (const float*)d_in[13];
    const float* lwhh = (const float*)d_in[14];
    const float* lbih = (const float*)d_in[15];
    const float* lbhh = (const float*)d_in[16];
    const int*   eidx = (const int*)d_in[17];
    const int*   gidx = (const int*)d_in[18];
    const int* src = eidx;
    const int* dst = eidx + N_EDGES;
    float* out = (float*)d_out;
    float* h   = out + (size_t)N_GRAPHS * 64;   // fp32 node state (final) in d_out tail

    char* ws = (char*)d_ws;
    size_t off = 0;
    auto alloc = [&](size_t bytes) -> void* {
        void* p = ws + off;
        off = (off + bytes + 255) & ~(size_t)255;
        return p;
    };
    float* sbuf  = (float*)alloc((size_t)N_NODES * DIM * 4);   // 12.8 MB
    float* cnt   = (float*)alloc((size_t)N_NODES * 4);
    _Float16* h16 = (_Float16*)alloc((size_t)N_NODES * DIM * 2); // 6.4 MB
    int*   gstart = (int*)alloc((size_t)(N_GRAPHS + 1) * 4);
    _Float16* w2f  = (_Float16*)alloc((size_t)W2F_HALFS * 2);  // 272 KB
    _Float16* gw   = (_Float16*)alloc((size_t)16384);          // prepacked GRU weights
    size_t fixed = off;
    size_t avail = ws_size > fixed ? ws_size - fixed : 0;

    auto need = [&](int nc) -> size_t {
        int cbk = (MSG_BLOCKS + nc - 1) / nc;
        return (size_t)cbk * 16 * 4096;   // 16 tiles/block * 4 KB/tile
    };
    int nchunk = 1;
    while (nchunk < 64 && need(nchunk) > avail) nchunk <<= 1;
    int chunk_blocks = (MSG_BLOCKS + nchunk - 1) / nchunk;
    _Float16* hwf = (_Float16*)alloc(need(nchunk));

    // ---- prologue (3 dispatches) ----
    lin0_kernel<<<dim3((N_NODES + 31) / 32), dim3(256), 0, stream>>>(
        nf, l0w, l0b, h16, cnt, sbuf);
    aux_kernel<<<dim3(CNT_BLOCKS + OFFS_BLOCKS + GRUW_BLOCKS + W2F_BLOCKS), dim3(256), 0, stream>>>(
        dst, cnt, gidx, gstart, gwih, gwhh, gw, w2, b2, w2f);
    if (nchunk == 1) {
        hw_kernel<<<dim3(MSG_BLOCKS * 8), dim3(256), 0, stream>>>(ef, w1, b1, hwf, 0);
    }

    // ---- 3 message-passing + GRU iterations (6 dispatches) ----
    for (int it = 0; it < 3; ++it) {
        for (int cix = 0; cix < nchunk; ++cix) {
            int bstart = cix * chunk_blocks;
            int bc = MSG_BLOCKS - bstart;
            if (bc <= 0) break;
            if (bc > chunk_blocks) bc = chunk_blocks;
            int e_off = bstart * 256;
            if (nchunk > 1)
                hw_kernel<<<dim3(bc * 8), dim3(256), 0, stream>>>(ef, w1, b1, hwf, e_off);
            msg_kernel<<<dim3(bc), dim3(256), 0, stream>>>(hwf, w2f, h16, src, dst, sbuf, e_off);
        }
        gru_kernel<<<dim3((N_NODES + 127) / 128), dim3(256), 0, stream>>>(
            sbuf, cnt, cb, gw, gbih, gbhh, h16, h, it == 2 ? 1 : 0);
    }

    // ---- Set2Set: single kernel, all 3 steps in registers (1 dispatch) ----
    s2s_kernel<<<dim3((N_GRAPHS + 7) / 8), dim3(256), 0, stream>>>(
        lwih, lwhh, lbih, lbhh, h, gstart, out);
}